// Round 1
// baseline (531.297 us; speedup 1.0000x reference)
//
#include <hip/hip_runtime.h>

#define AS1 __attribute__((address_space(1)))
#define AS3 __attribute__((address_space(3)))

typedef __bf16 bf16_t;
typedef __bf16 bf16x8 __attribute__((ext_vector_type(8)));
typedef __bf16 bf16x4 __attribute__((ext_vector_type(4)));
typedef float  floatx4 __attribute__((ext_vector_type(4)));
typedef unsigned int uint2_ __attribute__((ext_vector_type(2)));
typedef unsigned int uint4_ __attribute__((ext_vector_type(4)));

#define MFMA_BF16(a, b, c) __builtin_amdgcn_mfma_f32_16x16x32_bf16(a, b, c, 0, 0, 0)

static constexpr int T_  = 2048;
static constexpr int D_  = 3584;
static constexpr int NH_ = 28;   // query heads
static constexpr int KV_ = 4;    // kv heads
static constexpr int H_  = 128;  // head dim
static constexpr int NW_ = 36;   // 28 q + 4 k + 4 v projection heads
static constexpr int FPH_ = 40;  // split-s work items per head: sum_qb ceil((qb+1)/4)

// ---------------------------------------------------------------------------
// Elementwise fp32 -> bf16 convert (8 elems/thread)
// ---------------------------------------------------------------------------
__global__ void convert_f32_bf16(const float* __restrict__ src, bf16_t* __restrict__ dst) {
    const long i = (long)(blockIdx.x * blockDim.x + threadIdx.x) * 8;
    float4 a = ((const float4*)(src + i))[0];
    float4 b = ((const float4*)(src + i))[1];
    bf16x8 o = {(bf16_t)a.x, (bf16_t)a.y, (bf16_t)a.z, (bf16_t)a.w,
                (bf16_t)b.x, (bf16_t)b.y, (bf16_t)b.z, (bf16_t)b.w};
    *(bf16x8*)(dst + i) = o;
}

// ---------------------------------------------------------------------------
// 64x64-tile fp32 -> bf16 transpose, vectorized: dst[c][r] = (bf16)src[r][c]
// ---------------------------------------------------------------------------
__global__ __launch_bounds__(256) void transpose64_f32_bf16(const float* __restrict__ src,
                                                            bf16_t* __restrict__ dst,
                                                            int R, int C, long sStride, long dStride) {
    __shared__ bf16_t t[64][68];
    src += (long)blockIdx.z * sStride;
    dst += (long)blockIdx.z * dStride;
    const int tid = threadIdx.x;
    const int r0 = blockIdx.y * 64, c0 = blockIdx.x * 64;
#pragma unroll
    for (int p = 0; p < 4; p++) {
        const int row = (tid >> 4) + p * 16, col4 = tid & 15;
        float4 v = *(const float4*)(src + (long)(r0 + row) * C + c0 + col4 * 4);
        bf16x4 b = {(bf16_t)v.x, (bf16_t)v.y, (bf16_t)v.z, (bf16_t)v.w};
        *(bf16x4*)&t[row][col4 * 4] = b;
    }
    __syncthreads();
#pragma unroll
    for (int p = 0; p < 2; p++) {
        const int cc = (tid >> 3) + p * 32, k = tid & 7;
        bf16x8 o;
#pragma unroll
        for (int j = 0; j < 8; j++) o[j] = t[8 * k + j][cc];
        *(bf16x8*)(dst + (long)(c0 + cc) * R + r0 + 8 * k) = o;
    }
}

// ---------------------------------------------------------------------------
// Small 32x32 bf16 transpose (used for V^T only, 2 MB)
// ---------------------------------------------------------------------------
__global__ void transpose32_bf16(const bf16_t* __restrict__ src, bf16_t* __restrict__ dst,
                                 int R, int C, long sStride, long dStride) {
    __shared__ bf16_t tile[32][33];
    src += (long)blockIdx.z * sStride;
    dst += (long)blockIdx.z * dStride;
    const int tx = threadIdx.x & 31, ty = threadIdx.x >> 5;
    const int r0 = blockIdx.y * 32, c0 = blockIdx.x * 32;
#pragma unroll
    for (int i = 0; i < 4; i++) {
        int rr = ty + i * 8;
        tile[rr][tx] = src[(long)(r0 + rr) * C + c0 + tx];
    }
    __syncthreads();
#pragma unroll
    for (int i = 0; i < 4; i++) {
        int cc = ty + i * 8;
        dst[(long)(c0 + cc) * R + r0 + tx] = tile[tx][cc];
    }
}

// ---------------------------------------------------------------------------
// m97-style 128x128 GEMM core: C = A[128 x K] * Bt[128 x K]^T, fp32 acc.
// ---------------------------------------------------------------------------
__device__ __forceinline__ void gemm_core_128x128(const bf16_t* __restrict__ Arows, int lda,
                                                  const bf16_t* __restrict__ Brows, int ldb,
                                                  int K, floatx4 acc[4][4]) {
    __shared__ bf16_t As[128 * 32];
    __shared__ bf16_t Bs[128 * 32];
    const int tid = threadIdx.x;
    const int w = tid >> 6, l = tid & 63;
    const int lr = l >> 2, lc = l & 3;
    const int m16 = l & 15, quad = l >> 4;
    const int wr = w >> 1, wc = w & 1;
#pragma unroll
    for (int i = 0; i < 4; i++)
#pragma unroll
        for (int j = 0; j < 4; j++) acc[i][j] = (floatx4){0.f, 0.f, 0.f, 0.f};

    for (int kt = 0; kt < K; kt += 32) {
        __syncthreads();
#pragma unroll
        for (int is = 0; is < 2; is++) {
            const int row = 32 * w + 16 * is + lr;
            __builtin_amdgcn_global_load_lds((const AS1 void*)(Arows + (long)row * lda + kt + lc * 8),
                                             (AS3 void*)(As + row * 32 + lc * 8), 16, 0, 0);
            __builtin_amdgcn_global_load_lds((const AS1 void*)(Brows + (long)row * ldb + kt + lc * 8),
                                             (AS3 void*)(Bs + row * 32 + lc * 8), 16, 0, 0);
        }
        __syncthreads();
        bf16x8 af[4], bfr[4];
#pragma unroll
        for (int i = 0; i < 4; i++)
            af[i] = *(const bf16x8*)(As + (64 * wr + 16 * i + m16) * 32 + quad * 8);
#pragma unroll
        for (int j = 0; j < 4; j++)
            bfr[j] = *(const bf16x8*)(Bs + (64 * wc + 16 * j + m16) * 32 + quad * 8);
#pragma unroll
        for (int i = 0; i < 4; i++)
#pragma unroll
            for (int j = 0; j < 4; j++) acc[i][j] = MFMA_BF16(af[i], bfr[j], acc[i][j]);
    }
}

// QKV projection: out[hd][t][h] = x[t][:] . w[hd][:][h] + bias[hd][h]
__global__ __launch_bounds__(256) void gemm_qkv_kernel(const bf16_t* __restrict__ X,
                                                       const bf16_t* __restrict__ Wt,
                                                       const float* __restrict__ bq,
                                                       const float* __restrict__ bk,
                                                       const float* __restrict__ bv,
                                                       bf16_t* __restrict__ out) {
    const int mt = blockIdx.x, hd = blockIdx.y;
    const float* bias = hd < NH_ ? bq + hd * H_
                                 : (hd < NH_ + KV_ ? bk + (hd - NH_) * H_ : bv + (hd - NH_ - KV_) * H_);
    floatx4 acc[4][4];
    gemm_core_128x128(X + (long)mt * 128 * D_, D_, Wt + (long)hd * H_ * D_, D_, D_, acc);
    const int l = threadIdx.x & 63, w = threadIdx.x >> 6;
    const int m16 = l & 15, quad = l >> 4, wr = w >> 1, wc = w & 1;
    bf16_t* C = out + (long)hd * T_ * H_ + (long)mt * 128 * H_;
#pragma unroll
    for (int j = 0; j < 4; j++) {
        const int col = 64 * wc + 16 * j + m16;
        const float bb = bias[col];
#pragma unroll
        for (int i = 0; i < 4; i++) {
            const int row = 64 * wr + 16 * i + quad * 4;
#pragma unroll
            for (int r = 0; r < 4; r++) C[(row + r) * H_ + col] = (bf16_t)(acc[i][j][r] + bb);
        }
    }
}

// Output projection: out[t][d] = ctx[t][:] . woT[d][:]  (fp32 output)
__global__ __launch_bounds__(256) void gemm_out_kernel(const bf16_t* __restrict__ A,
                                                       const bf16_t* __restrict__ Bt,
                                                       float* __restrict__ Cg) {
    const int mt = blockIdx.x, nt = blockIdx.y;
    floatx4 acc[4][4];
    gemm_core_128x128(A + (long)mt * 128 * D_, D_, Bt + (long)nt * 128 * D_, D_, D_, acc);
    const int l = threadIdx.x & 63, w = threadIdx.x >> 6;
    const int m16 = l & 15, quad = l >> 4, wr = w >> 1, wc = w & 1;
    float* C = Cg + (long)mt * 128 * D_ + nt * 128;
#pragma unroll
    for (int j = 0; j < 4; j++) {
        const int col = 64 * wc + 16 * j + m16;
#pragma unroll
        for (int i = 0; i < 4; i++) {
            const int row = 64 * wr + 16 * i + quad * 4;
#pragma unroll
            for (int r = 0; r < 4; r++) C[(long)(row + r) * D_ + col] = acc[i][j][r];
        }
    }
}

// ---------------------------------------------------------------------------
// In-place RoPE on q (heads 0..27, scaled by H^-0.5) and k (heads 28..31)
// ---------------------------------------------------------------------------
__global__ void rope_kernel(bf16_t* __restrict__ qkv, const int* __restrict__ pos) {
    const int idx = blockIdx.x * blockDim.x + threadIdx.x;
    const int h = idx & 63;
    const int t = (idx >> 6) & (T_ - 1);
    const int hd = idx >> 17;
    if (hd >= NH_ + KV_) return;
    bf16_t* p = qkv + ((long)hd * T_ + t) * H_;
    const float x1 = (float)p[h], x2 = (float)p[h + 64];
    const float inv = expf(-(float)h * (13.815510557964274f / 64.f));
    const float ang = (float)pos[t] * inv;
    float s, c;
    sincosf(ang, &s, &c);
    float o1 = x1 * c - x2 * s;
    float o2 = x2 * c + x1 * s;
    if (hd < NH_) { o1 *= 0.08838834764831845f; o2 *= 0.08838834764831845f; }
    p[h] = (bf16_t)o1;
    p[h + 64] = (bf16_t)o2;
}

// ---------------------------------------------------------------------------
// Split-s flash attention. Work item = (head, q-tile of 128, s-chunk of 512).
//
// R5 rewrite:
//  * K/V staged via global_load_lds (async DMA, no VGPR round-trip); source
//    addresses pre-XOR-swizzled (16B chunk ^ (row&7)) so the LINEAR LDS image
//    is swizzled -> conflict-free ds_read_b128 column slices (G4/G21/m173).
//  * P never touches LDS: packed to bf16 in-register, redistributed from the
//    QK^T C-layout (s = quad*4+r) to the PV B-fragment layout (s = quad*8+j)
//    with 32 __shfl + selects per wave per s-block. Kills the Ps buffer, its
//    traffic, and the 3rd barrier (2 barriers/s-block now).
//  * LDS: 54272 -> 32768 B. If VGPR <= 128 this allows 4 blocks/CU (16 waves).
//  * __launch_bounds__(256) only — do NOT force min-waves (R4: spill disaster).
// ---------------------------------------------------------------------------
__global__ __launch_bounds__(256) void attn_kernel(const bf16_t* __restrict__ qkv,
                                                   const bf16_t* __restrict__ vT,
                                                   bf16_t* __restrict__ Opart,
                                                   float* __restrict__ ml) {
    __shared__ bf16_t smem[64 * 128 + 128 * 64];   // Ks[64][128] + Vs[128][64], both swizzled
    bf16_t* Ks = smem;
    bf16_t* Vs = smem + 64 * 128;

    const int n = blockIdx.y;
    int qb = 0, rem = blockIdx.x;
    while (true) { int ch = (qb + 4) >> 2; if (rem < ch) break; rem -= ch; qb++; }
    const long pidx = (long)n * FPH_ + blockIdx.x;

    const int kvh = n / 7;
    const bf16_t* Q  = qkv + (long)n * T_ * H_;
    const bf16_t* Kg = qkv + (long)(NH_ + kvh) * T_ * H_;
    const bf16_t* Vg = vT + (long)kvh * H_ * T_;  // [h][t]

    const int tid = threadIdx.x, w = tid >> 6, l = tid & 63;
    const int m16 = l & 15, quad = l >> 4;
    const int q0 = qb * 128 + w * 32;

    // Per-lane swizzled global source offsets (elements). LDS dest is linear:
    // chunk i*256+tid at byte (i*256+tid)*16 -> wave-uniform base + lane*16.
    int kOff[4], vOff[4];
#pragma unroll
    for (int i = 0; i < 4; i++) {
        const int ck_ = i * 256 + tid;           // K: 64 rows x 16 chunks
        const int kr = ck_ >> 4, kc = ck_ & 15;
        kOff[i] = kr * H_ + ((kc ^ (kr & 7)) << 3);
        const int vr = ck_ >> 3, vc = ck_ & 7;   // V: 128 rows x 8 chunks
        vOff[i] = vr * T_ + ((vc ^ (vr & 7)) << 3);
    }

    bf16x8 qf[2][4];
#pragma unroll
    for (int qt = 0; qt < 2; qt++)
#pragma unroll
        for (int kk = 0; kk < 4; kk++)
            qf[qt][kk] = *(const bf16x8*)(Q + (long)(q0 + qt * 16 + m16) * H_ + kk * 32 + quad * 8);

    floatx4 ot[2][8];
#pragma unroll
    for (int qt = 0; qt < 2; qt++)
#pragma unroll
        for (int ht = 0; ht < 8; ht++) ot[qt][ht] = (floatx4){0.f, 0.f, 0.f, 0.f};
    float mi[2] = {-1e30f, -1e30f}, li[2] = {0.f, 0.f};

    const int sb0 = rem * 8;
    const int sbE = min(sb0 + 8, 2 * qb + 2);

    // shuffle source lanes for the P redistribution (loop-invariant)
    const int s0 = m16 + ((quad & 1) << 5);
    const int s1 = s0 + 16;
    const bool hi = (quad & 2) != 0;

    for (int sb = sb0; sb < sbE; sb++) {
        __syncthreads();                         // prev-iter LDS reads done
        {
            const long kBase = (long)sb * 64 * H_;
            const int  vBase = sb * 64;
#pragma unroll
            for (int i = 0; i < 4; i++)
                __builtin_amdgcn_global_load_lds((const AS1 void*)(Kg + kBase + kOff[i]),
                                                 (AS3 void*)(Ks + (i * 256 + tid) * 8), 16, 0, 0);
#pragma unroll
            for (int i = 0; i < 4; i++)
                __builtin_amdgcn_global_load_lds((const AS1 void*)(Vg + vBase + vOff[i]),
                                                 (AS3 void*)(Vs + (i * 256 + tid) * 8), 16, 0, 0);
        }
        __syncthreads();                         // compiler drains vmcnt(0) before s_barrier

        // S^T[s][q] = sum_h K[s][h] Q[q][h]; swizzled conflict-free kf reads
        floatx4 stv[2][4];
#pragma unroll
        for (int ts = 0; ts < 4; ts++) {
            bf16x8 kf[4];
#pragma unroll
            for (int kk = 0; kk < 4; kk++)
                kf[kk] = *(const bf16x8*)(Ks + (16 * ts + m16) * 128 +
                                          ((((kk << 2) + quad) ^ (m16 & 7)) << 3));
#pragma unroll
            for (int qt = 0; qt < 2; qt++) {
                floatx4 c = (floatx4){0.f, 0.f, 0.f, 0.f};
#pragma unroll
                for (int kk = 0; kk < 4; kk++) c = MFMA_BF16(kf[kk], qf[qt][kk], c);
                stv[qt][ts] = c;
            }
        }

        // online softmax; pack P rows to bf16 words in-register
        unsigned int W[2][4][2];
        const bool need_mask = (sb * 64 + 63) > q0;
#pragma unroll
        for (int qt = 0; qt < 2; qt++) {
            const int qg = q0 + qt * 16 + m16;
            if (need_mask) {
#pragma unroll
                for (int ts = 0; ts < 4; ts++)
#pragma unroll
                    for (int r = 0; r < 4; r++) {
                        const int sg = sb * 64 + ts * 16 + quad * 4 + r;
                        if (sg > qg) stv[qt][ts][r] = -1e30f;
                    }
            }
            float mx = -1e30f;
#pragma unroll
            for (int ts = 0; ts < 4; ts++)
#pragma unroll
                for (int r = 0; r < 4; r++) mx = fmaxf(mx, stv[qt][ts][r]);
            mx = fmaxf(mx, __shfl_xor(mx, 16));
            mx = fmaxf(mx, __shfl_xor(mx, 32));
            const float mn = fmaxf(mi[qt], mx);
            const float alpha = __expf(mi[qt] - mn);
            mi[qt] = mn;
            float rs = 0.f;
#pragma unroll
            for (int ts = 0; ts < 4; ts++) {
                const float p0 = __expf(stv[qt][ts][0] - mn);
                const float p1 = __expf(stv[qt][ts][1] - mn);
                const float p2 = __expf(stv[qt][ts][2] - mn);
                const float p3 = __expf(stv[qt][ts][3] - mn);
                rs += p0 + p1 + p2 + p3;
                bf16x4 pv = {(bf16_t)p0, (bf16_t)p1, (bf16_t)p2, (bf16_t)p3};
                uint2_ u = __builtin_bit_cast(uint2_, pv);
                W[qt][ts][0] = u.x;
                W[qt][ts][1] = u.y;
            }
            rs += __shfl_xor(rs, 16);
            rs += __shfl_xor(rs, 32);
            li[qt] = li[qt] * alpha + rs;
#pragma unroll
            for (int ht = 0; ht < 8; ht++) ot[qt][ht] *= alpha;
        }

        // O^T[h][q] += sum_s V^T[h][s] P^T[s][q].
        // B-fragment needs s = quad*8+j; lane holds s = quadS*4+r. Redistribute:
        // pf[qt][ck] word wj = W[qt][2ck + (quad>>1)][wj&1] from lane
        //   m16 + 16*(2*(quad&1) + (wj>>1)).
#pragma unroll
        for (int ck = 0; ck < 2; ck++) {
            bf16x8 pf[2];
#pragma unroll
            for (int qt = 0; qt < 2; qt++) {
                const unsigned a0 = W[qt][2 * ck][0], a1 = W[qt][2 * ck][1];
                const unsigned b0 = W[qt][2 * ck + 1][0], b1 = W[qt][2 * ck + 1][1];
                unsigned pw0, pw1, pw2, pw3;
                { const unsigned xa = __shfl((int)a0, s0), xb = __shfl((int)b0, s0); pw0 = hi ? xb : xa; }
                { const unsigned xa = __shfl((int)a1, s0), xb = __shfl((int)b1, s0); pw1 = hi ? xb : xa; }
                { const unsigned xa = __shfl((int)a0, s1), xb = __shfl((int)b0, s1); pw2 = hi ? xb : xa; }
                { const unsigned xa = __shfl((int)a1, s1), xb = __shfl((int)b1, s1); pw3 = hi ? xb : xa; }
                uint4_ pv4 = {pw0, pw1, pw2, pw3};
                pf[qt] = __builtin_bit_cast(bf16x8, pv4);
            }
#pragma unroll
            for (int ht = 0; ht < 8; ht++) {
                bf16x8 vf = *(const bf16x8*)(Vs + (16 * ht + m16) * 64 +
                                             ((((ck << 2) + quad) ^ (m16 & 7)) << 3));
                ot[0][ht] = MFMA_BF16(vf, pf[0], ot[0][ht]);
                ot[1][ht] = MFMA_BF16(vf, pf[1], ot[1][ht]);
            }
        }
    }

    // write m/l partials (one lane per q-row: quad 0)
#pragma unroll
    for (int qt = 0; qt < 2; qt++) {
        if (quad == 0) {
            const int row = w * 32 + qt * 16 + m16;
            ml[pidx * 256 + row] = mi[qt];
            ml[pidx * 256 + 128 + row] = li[qt];
        }
    }

    // Epilogue: normalize, transpose O^T -> O via swizzled per-wave LDS, store
    __syncthreads();
    const float inv0 = 1.f / li[0], inv1 = 1.f / li[1];
    bf16_t* Oq = smem + w * (32 * 128);          // 8 KB/wave, XOR-swizzled rows of 256 B
#pragma unroll
    for (int qt = 0; qt < 2; qt++) {
        const float inv = qt ? inv1 : inv0;
        const int r = qt * 16 + m16;
#pragma unroll
        for (int ht = 0; ht < 8; ht++) {
            bf16x4 v = {(bf16_t)(ot[qt][ht][0] * inv), (bf16_t)(ot[qt][ht][1] * inv),
                        (bf16_t)(ot[qt][ht][2] * inv), (bf16_t)(ot[qt][ht][3] * inv)};
            const int chunk = (2 * ht + (quad >> 1)) ^ (r & 7);
            *(bf16x4*)((char*)Oq + r * 256 + (chunk << 4) + ((quad & 1) << 3)) = v;
        }
    }
    __syncthreads();
    {
        const int qrow = l >> 1, hf = l & 1;
        const int qloc = w * 32 + qrow;
        bf16_t* dst = Opart + (pidx * 128 + qloc) * 128 + hf * 64;
#pragma unroll
        for (int j = 0; j < 8; j++) {
            const bf16x8 o = *(const bf16x8*)((char*)Oq + qrow * 256 +
                                              ((((hf << 3) + j) ^ (qrow & 7)) << 4));
            *(bf16x8*)(dst + j * 8) = o;
        }
    }
}

// ---------------------------------------------------------------------------
// Combine partial attention chunks: ctx[t][n*H+h] = sum_c w_c * O_c
// ---------------------------------------------------------------------------
__global__ __launch_bounds__(256) void combine_kernel(const bf16_t* __restrict__ Opart,
                                                      const float* __restrict__ ml,
                                                      bf16_t* __restrict__ ctx) {
    const int qb = blockIdx.x, n = blockIdx.y;
    const int C = (qb + 4) >> 2;
    int f0 = 0;
    for (int i = 0; i < qb; i++) f0 += (i + 4) >> 2;
    const int tid = threadIdx.x;
    const int qrow = tid >> 1, half = tid & 1;
    const long pb = (long)n * FPH_ + f0;

    float m[4], lv[4], wv[4];
    float M = -1e30f;
    for (int c = 0; c < C; c++) {
        m[c] = ml[(pb + c) * 256 + qrow];
        lv[c] = ml[(pb + c) * 256 + 128 + qrow];
        M = fmaxf(M, m[c]);
    }
    float wsum = 0.f;
    for (int c = 0; c < C; c++) { wv[c] = lv[c] * __expf(m[c] - M); wsum += wv[c]; }
    const float invw = 1.f / wsum;
    for (int c = 0; c < C; c++) wv[c] *= invw;

    bf16_t* dst = ctx + ((long)(qb * 128 + qrow)) * (NH_ * H_) + n * H_ + half * 64;
#pragma unroll
    for (int j = 0; j < 8; j++) {
        float acc[8] = {0, 0, 0, 0, 0, 0, 0, 0};
        for (int c = 0; c < C; c++) {
            bf16x8 v = *(const bf16x8*)(Opart + ((pb + c) * 128 + qrow) * 128 + half * 64 + j * 8);
#pragma unroll
            for (int e = 0; e < 8; e++) acc[e] += wv[c] * (float)v[e];
        }
        bf16x8 o;
#pragma unroll
        for (int e = 0; e < 8; e++) o[e] = (bf16_t)acc[e];
        *(bf16x8*)(dst + j * 8) = o;
    }
}

// ---------------------------------------------------------------------------
extern "C" void kernel_launch(void* const* d_in, const int* in_sizes, int n_in,
                              void* d_out, int out_size, void* d_ws, size_t ws_size,
                              hipStream_t stream) {
    const float* x  = (const float*)d_in[0];
    const int*   ps = (const int*)d_in[1];
    const float* wq = (const float*)d_in[2];
    const float* bq = (const float*)d_in[3];
    const float* wk = (const float*)d_in[4];
    const float* bk = (const float*)d_in[5];
    const float* wv = (const float*)d_in[6];
    const float* bv = (const float*)d_in[7];
    const float* wo = (const float*)d_in[8];
    float* out = (float*)d_out;

    bf16_t* xb  = (bf16_t*)d_ws;                 // [2048][3584]    x in bf16
    bf16_t* wt  = xb + (long)T_ * D_;            // [36][128][3584] transposed qkv weights
    bf16_t* woT = wt + (long)NW_ * H_ * D_;      // [3584][3584]    woT[d][n*H+h]
    bf16_t* qkv = woT + (long)D_ * D_;           // [36][2048][128] projections
    bf16_t* vT  = qkv + (long)NW_ * T_ * H_;     // [4][128][2048]  V transposed
    bf16_t* ctx = vT + (long)KV_ * H_ * T_;      // [2048][3584]    attention output (bf16)
    // partials alias xb+wt (dead after gemm_qkv): 36.7 MB + 1.15 MB < 47.7 MB
    bf16_t* Opart = (bf16_t*)d_ws;               // [28*40][128][128] bf16
    float*  ml    = (float*)((char*)d_ws + (long)NH_ * FPH_ * 128 * 128 * 2);  // [28*40][2][128]

    const long whd = (long)D_ * H_;
    convert_f32_bf16<<<((long)T_ * D_ / 8 + 255) / 256, 256, 0, stream>>>(x, xb);
    transpose64_f32_bf16<<<dim3(H_ / 64, D_ / 64, NH_), 256, 0, stream>>>(wq, wt, D_, H_, whd, whd);
    transpose64_f32_bf16<<<dim3(H_ / 64, D_ / 64, KV_), 256, 0, stream>>>(wk, wt + (long)NH_ * whd, D_, H_, whd, whd);
    transpose64_f32_bf16<<<dim3(H_ / 64, D_ / 64, KV_), 256, 0, stream>>>(wv, wt + (long)(NH_ + KV_) * whd, D_, H_, whd, whd);
    transpose64_f32_bf16<<<dim3(D_ / 64, D_ / 64, 1), 256, 0, stream>>>(wo, woT, D_, D_, 0, 0);

    gemm_qkv_kernel<<<dim3(T_ / 128, NW_), 256, 0, stream>>>(xb, wt, bq, bk, bv, qkv);
    rope_kernel<<<(32 * T_ * 64) / 256, 256, 0, stream>>>(qkv, ps);
    transpose32_bf16<<<dim3(H_ / 32, T_ / 32, KV_), 256, 0, stream>>>(qkv + (long)(NH_ + KV_) * T_ * H_, vT,
                                                                      T_, H_, (long)T_ * H_, (long)T_ * H_);
    attn_kernel<<<dim3(FPH_, NH_), 256, 0, stream>>>(qkv, vT, Opart, ml);
    combine_kernel<<<dim3(T_ / 128, NH_), 256, 0, stream>>>(Opart, ml, ctx);
    gemm_out_kernel<<<dim3(T_ / 128, D_ / 128), 256, 0, stream>>>(ctx, woT, out);
}

// Round 2
// 530.618 us; speedup vs baseline: 1.0013x; 1.0013x over previous
//
#include <hip/hip_runtime.h>

#define AS1 __attribute__((address_space(1)))
#define AS3 __attribute__((address_space(3)))

typedef __bf16 bf16_t;
typedef __bf16 bf16x8 __attribute__((ext_vector_type(8)));
typedef __bf16 bf16x4 __attribute__((ext_vector_type(4)));
typedef float  floatx4 __attribute__((ext_vector_type(4)));
typedef unsigned int uint2_ __attribute__((ext_vector_type(2)));
typedef unsigned int uint4_ __attribute__((ext_vector_type(4)));

#define MFMA_BF16(a, b, c) __builtin_amdgcn_mfma_f32_16x16x32_bf16(a, b, c, 0, 0, 0)

static constexpr int T_  = 2048;
static constexpr int D_  = 3584;
static constexpr int NH_ = 28;   // query heads
static constexpr int KV_ = 4;    // kv heads
static constexpr int H_  = 128;  // head dim
static constexpr int NW_ = 36;   // 28 q + 4 k + 4 v projection heads
static constexpr int FPH_ = 40;  // split-s work items per head: sum_qb ceil((qb+1)/4)

// LOG2E folded into the q-scale so softmax runs in the exp2 domain
#define QSCALE 0.12754245778287616f   /* H^-0.5 * log2(e) */

// ---------------------------------------------------------------------------
// Elementwise fp32 -> bf16 convert (8 elems/thread)
// ---------------------------------------------------------------------------
__global__ void convert_f32_bf16(const float* __restrict__ src, bf16_t* __restrict__ dst) {
    const long i = (long)(blockIdx.x * blockDim.x + threadIdx.x) * 8;
    float4 a = ((const float4*)(src + i))[0];
    float4 b = ((const float4*)(src + i))[1];
    bf16x8 o = {(bf16_t)a.x, (bf16_t)a.y, (bf16_t)a.z, (bf16_t)a.w,
                (bf16_t)b.x, (bf16_t)b.y, (bf16_t)b.z, (bf16_t)b.w};
    *(bf16x8*)(dst + i) = o;
}

// ---------------------------------------------------------------------------
// 64x64-tile fp32 -> bf16 transpose, vectorized: dst[c][r] = (bf16)src[r][c]
// ---------------------------------------------------------------------------
__global__ __launch_bounds__(256) void transpose64_f32_bf16(const float* __restrict__ src,
                                                            bf16_t* __restrict__ dst,
                                                            int R, int C, long sStride, long dStride) {
    __shared__ bf16_t t[64][68];
    src += (long)blockIdx.z * sStride;
    dst += (long)blockIdx.z * dStride;
    const int tid = threadIdx.x;
    const int r0 = blockIdx.y * 64, c0 = blockIdx.x * 64;
#pragma unroll
    for (int p = 0; p < 4; p++) {
        const int row = (tid >> 4) + p * 16, col4 = tid & 15;
        float4 v = *(const float4*)(src + (long)(r0 + row) * C + c0 + col4 * 4);
        bf16x4 b = {(bf16_t)v.x, (bf16_t)v.y, (bf16_t)v.z, (bf16_t)v.w};
        *(bf16x4*)&t[row][col4 * 4] = b;
    }
    __syncthreads();
#pragma unroll
    for (int p = 0; p < 2; p++) {
        const int cc = (tid >> 3) + p * 32, k = tid & 7;
        bf16x8 o;
#pragma unroll
        for (int j = 0; j < 8; j++) o[j] = t[8 * k + j][cc];
        *(bf16x8*)(dst + (long)(c0 + cc) * R + r0 + 8 * k) = o;
    }
}

// ---------------------------------------------------------------------------
// Small 32x32 bf16 transpose (used for V^T only, 2 MB)
// ---------------------------------------------------------------------------
__global__ void transpose32_bf16(const bf16_t* __restrict__ src, bf16_t* __restrict__ dst,
                                 int R, int C, long sStride, long dStride) {
    __shared__ bf16_t tile[32][33];
    src += (long)blockIdx.z * sStride;
    dst += (long)blockIdx.z * dStride;
    const int tx = threadIdx.x & 31, ty = threadIdx.x >> 5;
    const int r0 = blockIdx.y * 32, c0 = blockIdx.x * 32;
#pragma unroll
    for (int i = 0; i < 4; i++) {
        int rr = ty + i * 8;
        tile[rr][tx] = src[(long)(r0 + rr) * C + c0 + tx];
    }
    __syncthreads();
#pragma unroll
    for (int i = 0; i < 4; i++) {
        int cc = ty + i * 8;
        dst[(long)(c0 + cc) * R + r0 + tx] = tile[tx][cc];
    }
}

// ---------------------------------------------------------------------------
// m97-style 128x128 GEMM core: C = A[128 x K] * Bt[128 x K]^T, fp32 acc.
// ---------------------------------------------------------------------------
__device__ __forceinline__ void gemm_core_128x128(const bf16_t* __restrict__ Arows, int lda,
                                                  const bf16_t* __restrict__ Brows, int ldb,
                                                  int K, floatx4 acc[4][4]) {
    __shared__ bf16_t As[128 * 32];
    __shared__ bf16_t Bs[128 * 32];
    const int tid = threadIdx.x;
    const int w = tid >> 6, l = tid & 63;
    const int lr = l >> 2, lc = l & 3;
    const int m16 = l & 15, quad = l >> 4;
    const int wr = w >> 1, wc = w & 1;
#pragma unroll
    for (int i = 0; i < 4; i++)
#pragma unroll
        for (int j = 0; j < 4; j++) acc[i][j] = (floatx4){0.f, 0.f, 0.f, 0.f};

    for (int kt = 0; kt < K; kt += 32) {
        __syncthreads();
#pragma unroll
        for (int is = 0; is < 2; is++) {
            const int row = 32 * w + 16 * is + lr;
            __builtin_amdgcn_global_load_lds((const AS1 void*)(Arows + (long)row * lda + kt + lc * 8),
                                             (AS3 void*)(As + row * 32 + lc * 8), 16, 0, 0);
            __builtin_amdgcn_global_load_lds((const AS1 void*)(Brows + (long)row * ldb + kt + lc * 8),
                                             (AS3 void*)(Bs + row * 32 + lc * 8), 16, 0, 0);
        }
        __syncthreads();
        bf16x8 af[4], bfr[4];
#pragma unroll
        for (int i = 0; i < 4; i++)
            af[i] = *(const bf16x8*)(As + (64 * wr + 16 * i + m16) * 32 + quad * 8);
#pragma unroll
        for (int j = 0; j < 4; j++)
            bfr[j] = *(const bf16x8*)(Bs + (64 * wc + 16 * j + m16) * 32 + quad * 8);
#pragma unroll
        for (int i = 0; i < 4; i++)
#pragma unroll
            for (int j = 0; j < 4; j++) acc[i][j] = MFMA_BF16(af[i], bfr[j], acc[i][j]);
    }
}

// QKV projection: out[hd][t][h] = x[t][:] . w[hd][:][h] + bias[hd][h]
__global__ __launch_bounds__(256) void gemm_qkv_kernel(const bf16_t* __restrict__ X,
                                                       const bf16_t* __restrict__ Wt,
                                                       const float* __restrict__ bq,
                                                       const float* __restrict__ bk,
                                                       const float* __restrict__ bv,
                                                       bf16_t* __restrict__ out) {
    const int mt = blockIdx.x, hd = blockIdx.y;
    const float* bias = hd < NH_ ? bq + hd * H_
                                 : (hd < NH_ + KV_ ? bk + (hd - NH_) * H_ : bv + (hd - NH_ - KV_) * H_);
    floatx4 acc[4][4];
    gemm_core_128x128(X + (long)mt * 128 * D_, D_, Wt + (long)hd * H_ * D_, D_, D_, acc);
    const int l = threadIdx.x & 63, w = threadIdx.x >> 6;
    const int m16 = l & 15, quad = l >> 4, wr = w >> 1, wc = w & 1;
    bf16_t* C = out + (long)hd * T_ * H_ + (long)mt * 128 * H_;
#pragma unroll
    for (int j = 0; j < 4; j++) {
        const int col = 64 * wc + 16 * j + m16;
        const float bb = bias[col];
#pragma unroll
        for (int i = 0; i < 4; i++) {
            const int row = 64 * wr + 16 * i + quad * 4;
#pragma unroll
            for (int r = 0; r < 4; r++) C[(row + r) * H_ + col] = (bf16_t)(acc[i][j][r] + bb);
        }
    }
}

// Output projection: out[t][d] = ctx[t][:] . woT[d][:]  (fp32 output)
__global__ __launch_bounds__(256) void gemm_out_kernel(const bf16_t* __restrict__ A,
                                                       const bf16_t* __restrict__ Bt,
                                                       float* __restrict__ Cg) {
    const int mt = blockIdx.x, nt = blockIdx.y;
    floatx4 acc[4][4];
    gemm_core_128x128(A + (long)mt * 128 * D_, D_, Bt + (long)nt * 128 * D_, D_, D_, acc);
    const int l = threadIdx.x & 63, w = threadIdx.x >> 6;
    const int m16 = l & 15, quad = l >> 4, wr = w >> 1, wc = w & 1;
    float* C = Cg + (long)mt * 128 * D_ + nt * 128;
#pragma unroll
    for (int j = 0; j < 4; j++) {
        const int col = 64 * wc + 16 * j + m16;
#pragma unroll
        for (int i = 0; i < 4; i++) {
            const int row = 64 * wr + 16 * i + quad * 4;
#pragma unroll
            for (int r = 0; r < 4; r++) C[(long)(row + r) * D_ + col] = acc[i][j][r];
        }
    }
}

// ---------------------------------------------------------------------------
// In-place RoPE on q (heads 0..27, scaled by H^-0.5 * log2e) and k (28..31)
// ---------------------------------------------------------------------------
__global__ void rope_kernel(bf16_t* __restrict__ qkv, const int* __restrict__ pos) {
    const int idx = blockIdx.x * blockDim.x + threadIdx.x;
    const int h = idx & 63;
    const int t = (idx >> 6) & (T_ - 1);
    const int hd = idx >> 17;
    if (hd >= NH_ + KV_) return;
    bf16_t* p = qkv + ((long)hd * T_ + t) * H_;
    const float x1 = (float)p[h], x2 = (float)p[h + 64];
    const float inv = expf(-(float)h * (13.815510557964274f / 64.f));
    const float ang = (float)pos[t] * inv;
    float s, c;
    sincosf(ang, &s, &c);
    float o1 = x1 * c - x2 * s;
    float o2 = x2 * c + x1 * s;
    if (hd < NH_) { o1 *= QSCALE; o2 *= QSCALE; }   // softmax runs in exp2 domain
    p[h] = (bf16_t)o1;
    p[h + 64] = (bf16_t)o2;
}

// ---------------------------------------------------------------------------
// Split-s flash attention — R6: true double-buffered pipeline.
//  * 4 SEPARATE __shared__ arrays (Ks0/Ks1/Vs0/Vs1) + 2x-unrolled loop so
//    buffer identity is STATIC -> LLVM alias analysis keeps the in-flight
//    global_load_lds (next tile) independent of this tile's ds_reads. The
//    only vmcnt(0) drain is the compiler's one before the single per-iter
//    s_barrier — at that point the loads have had a full compute phase in
//    flight, so the wait is ~free (T3 minimum 2-phase recipe).
//  * One barrier per s-block (was 2), s_setprio(1) around MFMA clusters (T5).
//  * Softmax in exp2 domain (log2e folded into q scale in rope_kernel).
//  * LDS 64 KB -> 2 blocks/CU; measured avg concurrency was <1 block/CU, so
//    the capacity loss (3->2) is not binding; per-block latency is.
// ---------------------------------------------------------------------------
__device__ __forceinline__ void attn_stage(const bf16_t* __restrict__ Kg,
                                           const bf16_t* __restrict__ Vg,
                                           int sb, int tid,
                                           const int kOff[4], const int vOff[4],
                                           bf16_t* Ks, bf16_t* Vs) {
    const long kBase = (long)sb * 64 * H_;
    const int  vBase = sb * 64;
#pragma unroll
    for (int i = 0; i < 4; i++)
        __builtin_amdgcn_global_load_lds((const AS1 void*)(Kg + kBase + kOff[i]),
                                         (AS3 void*)(Ks + (i * 256 + tid) * 8), 16, 0, 0);
#pragma unroll
    for (int i = 0; i < 4; i++)
        __builtin_amdgcn_global_load_lds((const AS1 void*)(Vg + vBase + vOff[i]),
                                         (AS3 void*)(Vs + (i * 256 + tid) * 8), 16, 0, 0);
}

__device__ __forceinline__ void attn_step(const bf16_t* __restrict__ Ks,
                                          const bf16_t* __restrict__ Vs,
                                          int sb, int q0, int m16, int quad, int w,
                                          int s0, int s1, bool hi,
                                          const bf16x8 qf[2][4], floatx4 ot[2][8],
                                          float mi[2], float li[2]) {
    // S^T[s][q] = sum_h K[s][h] Q[q][h]; swizzled conflict-free kf reads
    floatx4 stv[2][4];
    __builtin_amdgcn_s_setprio(1);
#pragma unroll
    for (int ts = 0; ts < 4; ts++) {
        bf16x8 kf[4];
#pragma unroll
        for (int kk = 0; kk < 4; kk++)
            kf[kk] = *(const bf16x8*)(Ks + (16 * ts + m16) * 128 +
                                      ((((kk << 2) + quad) ^ (m16 & 7)) << 3));
#pragma unroll
        for (int qt = 0; qt < 2; qt++) {
            floatx4 c = (floatx4){0.f, 0.f, 0.f, 0.f};
#pragma unroll
            for (int kk = 0; kk < 4; kk++) c = MFMA_BF16(kf[kk], qf[qt][kk], c);
            stv[qt][ts] = c;
        }
    }
    __builtin_amdgcn_s_setprio(0);

    // online softmax (exp2 domain); pack P rows to bf16 words in-register
    unsigned int W[2][4][2];
    const bool need_mask = (sb * 64 + 63) > q0;
#pragma unroll
    for (int qt = 0; qt < 2; qt++) {
        const int qg = q0 + qt * 16 + m16;
        if (need_mask) {
#pragma unroll
            for (int ts = 0; ts < 4; ts++)
#pragma unroll
                for (int r = 0; r < 4; r++) {
                    const int sg = sb * 64 + ts * 16 + quad * 4 + r;
                    if (sg > qg) stv[qt][ts][r] = -1e30f;
                }
        }
        float mx = -1e30f;
#pragma unroll
        for (int ts = 0; ts < 4; ts++)
#pragma unroll
            for (int r = 0; r < 4; r++) mx = fmaxf(mx, stv[qt][ts][r]);
        mx = fmaxf(mx, __shfl_xor(mx, 16));
        mx = fmaxf(mx, __shfl_xor(mx, 32));
        const float mn = fmaxf(mi[qt], mx);
        const float alpha = exp2f(mi[qt] - mn);
        mi[qt] = mn;
        float rs = 0.f;
#pragma unroll
        for (int ts = 0; ts < 4; ts++) {
            const float p0 = exp2f(stv[qt][ts][0] - mn);
            const float p1 = exp2f(stv[qt][ts][1] - mn);
            const float p2 = exp2f(stv[qt][ts][2] - mn);
            const float p3 = exp2f(stv[qt][ts][3] - mn);
            rs += p0 + p1 + p2 + p3;
            bf16x4 pv = {(bf16_t)p0, (bf16_t)p1, (bf16_t)p2, (bf16_t)p3};
            uint2_ u = __builtin_bit_cast(uint2_, pv);
            W[qt][ts][0] = u.x;
            W[qt][ts][1] = u.y;
        }
        rs += __shfl_xor(rs, 16);
        rs += __shfl_xor(rs, 32);
        li[qt] = li[qt] * alpha + rs;
#pragma unroll
        for (int ht = 0; ht < 8; ht++) ot[qt][ht] *= alpha;
    }

    // O^T[h][q] += sum_s V^T[h][s] P^T[s][q]; P redistributed via shfl
#pragma unroll
    for (int ck = 0; ck < 2; ck++) {
        bf16x8 pf[2];
#pragma unroll
        for (int qt = 0; qt < 2; qt++) {
            const unsigned a0 = W[qt][2 * ck][0], a1 = W[qt][2 * ck][1];
            const unsigned b0 = W[qt][2 * ck + 1][0], b1 = W[qt][2 * ck + 1][1];
            unsigned pw0, pw1, pw2, pw3;
            { const unsigned xa = __shfl((int)a0, s0), xb = __shfl((int)b0, s0); pw0 = hi ? xb : xa; }
            { const unsigned xa = __shfl((int)a1, s0), xb = __shfl((int)b1, s0); pw1 = hi ? xb : xa; }
            { const unsigned xa = __shfl((int)a0, s1), xb = __shfl((int)b0, s1); pw2 = hi ? xb : xa; }
            { const unsigned xa = __shfl((int)a1, s1), xb = __shfl((int)b1, s1); pw3 = hi ? xb : xa; }
            uint4_ pv4 = {pw0, pw1, pw2, pw3};
            pf[qt] = __builtin_bit_cast(bf16x8, pv4);
        }
        __builtin_amdgcn_s_setprio(1);
#pragma unroll
        for (int ht = 0; ht < 8; ht++) {
            bf16x8 vf = *(const bf16x8*)(Vs + (16 * ht + m16) * 64 +
                                         ((((ck << 2) + quad) ^ (m16 & 7)) << 3));
            ot[0][ht] = MFMA_BF16(vf, pf[0], ot[0][ht]);
            ot[1][ht] = MFMA_BF16(vf, pf[1], ot[1][ht]);
        }
        __builtin_amdgcn_s_setprio(0);
    }
}

__global__ __launch_bounds__(256) void attn_kernel(const bf16_t* __restrict__ qkv,
                                                   const bf16_t* __restrict__ vT,
                                                   bf16_t* __restrict__ Opart,
                                                   float* __restrict__ ml) {
    __shared__ bf16_t Ks0[64 * 128];   // separate objects: static buffer identity
    __shared__ bf16_t Ks1[64 * 128];
    __shared__ bf16_t Vs0[128 * 64];
    __shared__ bf16_t Vs1[128 * 64];

    const int n = blockIdx.y;
    int qb = 0, rem = blockIdx.x;
    while (true) { int ch = (qb + 4) >> 2; if (rem < ch) break; rem -= ch; qb++; }
    const long pidx = (long)n * FPH_ + blockIdx.x;

    const int kvh = n / 7;
    const bf16_t* Q  = qkv + (long)n * T_ * H_;
    const bf16_t* Kg = qkv + (long)(NH_ + kvh) * T_ * H_;
    const bf16_t* Vg = vT + (long)kvh * H_ * T_;  // [h][t]

    const int tid = threadIdx.x, w = tid >> 6, l = tid & 63;
    const int m16 = l & 15, quad = l >> 4;
    const int q0 = qb * 128 + w * 32;

    // Per-lane swizzled global source offsets (elements); LDS dest is linear.
    int kOff[4], vOff[4];
#pragma unroll
    for (int i = 0; i < 4; i++) {
        const int ck_ = i * 256 + tid;           // K: 64 rows x 16 chunks
        const int kr = ck_ >> 4, kc = ck_ & 15;
        kOff[i] = kr * H_ + ((kc ^ (kr & 7)) << 3);
        const int vr = ck_ >> 3, vc = ck_ & 7;   // V: 128 rows x 8 chunks
        vOff[i] = vr * T_ + ((vc ^ (vr & 7)) << 3);
    }

    bf16x8 qf[2][4];
#pragma unroll
    for (int qt = 0; qt < 2; qt++)
#pragma unroll
        for (int kk = 0; kk < 4; kk++)
            qf[qt][kk] = *(const bf16x8*)(Q + (long)(q0 + qt * 16 + m16) * H_ + kk * 32 + quad * 8);

    floatx4 ot[2][8];
#pragma unroll
    for (int qt = 0; qt < 2; qt++)
#pragma unroll
        for (int ht = 0; ht < 8; ht++) ot[qt][ht] = (floatx4){0.f, 0.f, 0.f, 0.f};
    float mi[2] = {-1e30f, -1e30f}, li[2] = {0.f, 0.f};

    const int sb0 = rem * 8;
    const int sbE = min(sb0 + 8, 2 * qb + 2);

    const int s0 = m16 + ((quad & 1) << 5);
    const int s1 = s0 + 16;
    const bool hi = (quad & 2) != 0;

    // ---- software pipeline: stage(sb0) ... {barrier; stage(next); compute} --
    attn_stage(Kg, Vg, sb0, tid, kOff, vOff, Ks0, Vs0);
    int sb = sb0;
    for (;;) {
        __syncthreads();                                  // drains loads -> buf0
        if (sb + 1 < sbE) attn_stage(Kg, Vg, sb + 1, tid, kOff, vOff, Ks1, Vs1);
        attn_step(Ks0, Vs0, sb, q0, m16, quad, w, s0, s1, hi, qf, ot, mi, li);
        if (++sb >= sbE) break;
        __syncthreads();                                  // drains loads -> buf1
        if (sb + 1 < sbE) attn_stage(Kg, Vg, sb + 1, tid, kOff, vOff, Ks0, Vs0);
        attn_step(Ks1, Vs1, sb, q0, m16, quad, w, s0, s1, hi, qf, ot, mi, li);
        if (++sb >= sbE) break;
    }

    // write m/l partials (one lane per q-row: quad 0)
#pragma unroll
    for (int qt = 0; qt < 2; qt++) {
        if (quad == 0) {
            const int row = w * 32 + qt * 16 + m16;
            ml[pidx * 256 + row] = mi[qt];
            ml[pidx * 256 + 128 + row] = li[qt];
        }
    }

    // Epilogue: normalize, transpose O^T -> O via swizzled per-wave LDS, store
    __syncthreads();
    const float inv0 = 1.f / li[0], inv1 = 1.f / li[1];
    bf16_t* Oq = (w < 2 ? Ks0 : Ks1) + (w & 1) * (32 * 128);   // 8 KB per wave
#pragma unroll
    for (int qt = 0; qt < 2; qt++) {
        const float inv = qt ? inv1 : inv0;
        const int r = qt * 16 + m16;
#pragma unroll
        for (int ht = 0; ht < 8; ht++) {
            bf16x4 v = {(bf16_t)(ot[qt][ht][0] * inv), (bf16_t)(ot[qt][ht][1] * inv),
                        (bf16_t)(ot[qt][ht][2] * inv), (bf16_t)(ot[qt][ht][3] * inv)};
            const int chunk = (2 * ht + (quad >> 1)) ^ (r & 7);
            *(bf16x4*)((char*)Oq + r * 256 + (chunk << 4) + ((quad & 1) << 3)) = v;
        }
    }
    __syncthreads();
    {
        const int qrow = l >> 1, hf = l & 1;
        const int qloc = w * 32 + qrow;
        bf16_t* dst = Opart + (pidx * 128 + qloc) * 128 + hf * 64;
#pragma unroll
        for (int j = 0; j < 8; j++) {
            const bf16x8 o = *(const bf16x8*)((char*)Oq + qrow * 256 +
                                              ((((hf << 3) + j) ^ (qrow & 7)) << 4));
            *(bf16x8*)(dst + j * 8) = o;
        }
    }
}

// ---------------------------------------------------------------------------
// Combine partial attention chunks: ctx[t][n*H+h] = sum_c w_c * O_c
// NOTE: ml values are in the exp2 domain -> use exp2f here.
// ---------------------------------------------------------------------------
__global__ __launch_bounds__(256) void combine_kernel(const bf16_t* __restrict__ Opart,
                                                      const float* __restrict__ ml,
                                                      bf16_t* __restrict__ ctx) {
    const int qb = blockIdx.x, n = blockIdx.y;
    const int C = (qb + 4) >> 2;
    int f0 = 0;
    for (int i = 0; i < qb; i++) f0 += (i + 4) >> 2;
    const int tid = threadIdx.x;
    const int qrow = tid >> 1, half = tid & 1;
    const long pb = (long)n * FPH_ + f0;

    float m[4], lv[4], wv[4];
    float M = -1e30f;
    for (int c = 0; c < C; c++) {
        m[c] = ml[(pb + c) * 256 + qrow];
        lv[c] = ml[(pb + c) * 256 + 128 + qrow];
        M = fmaxf(M, m[c]);
    }
    float wsum = 0.f;
    for (int c = 0; c < C; c++) { wv[c] = lv[c] * exp2f(m[c] - M); wsum += wv[c]; }
    const float invw = 1.f / wsum;
    for (int c = 0; c < C; c++) wv[c] *= invw;

    bf16_t* dst = ctx + ((long)(qb * 128 + qrow)) * (NH_ * H_) + n * H_ + half * 64;
#pragma unroll
    for (int j = 0; j < 8; j++) {
        float acc[8] = {0, 0, 0, 0, 0, 0, 0, 0};
        for (int c = 0; c < C; c++) {
            bf16x8 v = *(const bf16x8*)(Opart + ((pb + c) * 128 + qrow) * 128 + half * 64 + j * 8);
#pragma unroll
            for (int e = 0; e < 8; e++) acc[e] += wv[c] * (float)v[e];
        }
        bf16x8 o;
#pragma unroll
        for (int e = 0; e < 8; e++) o[e] = (bf16_t)acc[e];
        *(bf16x8*)(dst + j * 8) = o;
    }
}

// ---------------------------------------------------------------------------
extern "C" void kernel_launch(void* const* d_in, const int* in_sizes, int n_in,
                              void* d_out, int out_size, void* d_ws, size_t ws_size,
                              hipStream_t stream) {
    const float* x  = (const float*)d_in[0];
    const int*   ps = (const int*)d_in[1];
    const float* wq = (const float*)d_in[2];
    const float* bq = (const float*)d_in[3];
    const float* wk = (const float*)d_in[4];
    const float* bk = (const float*)d_in[5];
    const float* wv = (const float*)d_in[6];
    const float* bv = (const float*)d_in[7];
    const float* wo = (const float*)d_in[8];
    float* out = (float*)d_out;

    bf16_t* xb  = (bf16_t*)d_ws;                 // [2048][3584]    x in bf16
    bf16_t* wt  = xb + (long)T_ * D_;            // [36][128][3584] transposed qkv weights
    bf16_t* woT = wt + (long)NW_ * H_ * D_;      // [3584][3584]    woT[d][n*H+h]
    bf16_t* qkv = woT + (long)D_ * D_;           // [36][2048][128] projections
    bf16_t* vT  = qkv + (long)NW_ * T_ * H_;     // [4][128][2048]  V transposed
    bf16_t* ctx = vT + (long)KV_ * H_ * T_;      // [2048][3584]    attention output (bf16)
    // partials alias xb+wt (dead after gemm_qkv): 36.7 MB + 1.15 MB < 47.7 MB
    bf16_t* Opart = (bf16_t*)d_ws;               // [28*40][128][128] bf16
    float*  ml    = (float*)((char*)d_ws + (long)NH_ * FPH_ * 128 * 128 * 2);  // [28*40][2][128]

    const long whd = (long)D_ * H_;
    convert_f32_bf16<<<((long)T_ * D_ / 8 + 255) / 256, 256, 0, stream>>>(x, xb);
    transpose64_f32_bf16<<<dim3(H_ / 64, D_ / 64, NH_), 256, 0, stream>>>(wq, wt, D_, H_, whd, whd);
    transpose64_f32_bf16<<<dim3(H_ / 64, D_ / 64, KV_), 256, 0, stream>>>(wk, wt + (long)NH_ * whd, D_, H_, whd, whd);
    transpose64_f32_bf16<<<dim3(H_ / 64, D_ / 64, KV_), 256, 0, stream>>>(wv, wt + (long)(NH_ + KV_) * whd, D_, H_, whd, whd);
    transpose64_f32_bf16<<<dim3(D_ / 64, D_ / 64, 1), 256, 0, stream>>>(wo, woT, D_, D_, 0, 0);

    gemm_qkv_kernel<<<dim3(T_ / 128, NW_), 256, 0, stream>>>(xb, wt, bq, bk, bv, qkv);
    rope_kernel<<<(32 * T_ * 64) / 256, 256, 0, stream>>>(qkv, ps);
    transpose32_bf16<<<dim3(H_ / 32, T_ / 32, KV_), 256, 0, stream>>>(qkv + (long)(NH_ + KV_) * T_ * H_, vT,
                                                                      T_, H_, (long)T_ * H_, (long)T_ * H_);
    attn_kernel<<<dim3(FPH_, NH_), 256, 0, stream>>>(qkv, vT, Opart, ml);
    combine_kernel<<<dim3(T_ / 128, NH_), 256, 0, stream>>>(Opart, ml, ctx);
    gemm_out_kernel<<<dim3(T_ / 128, D_ / 128), 256, 0, stream>>>(ctx, woT, out);
}